// Round 3
// baseline (3604.631 us; speedup 1.0000x reference)
//
#include <hip/hip_runtime.h>

typedef unsigned short u16;
typedef unsigned int u32;
typedef __attribute__((ext_vector_type(8))) short bf16x8;
typedef __attribute__((ext_vector_type(4))) float f32x4;

__device__ __forceinline__ float b2f(u16 u) { return __uint_as_float(((u32)u) << 16); }
__device__ __forceinline__ u16 f2b(float f) {
  u32 u = __float_as_uint(f);
  return (u16)((u + 0x7FFFu + ((u >> 16) & 1u)) >> 16);
}

__device__ __forceinline__ void gld_lds16(const void* g, void* l) {
  __builtin_amdgcn_global_load_lds((const __attribute__((address_space(1))) u32*)g,
                                   (__attribute__((address_space(3))) u32*)l, 16, 0, 0);
}

// ---------------- adp = softmax(relu(nv1@nv2), axis=1), bf16, row-major (v,w) ----------------
__global__ __launch_bounds__(256) void k_adp(const float* __restrict__ nv1,
                                             const float* __restrict__ nv2,
                                             u16* __restrict__ adp) {
  int v = blockIdx.x, t = threadIdx.x;
  __shared__ float red[8];
  const float* nrow = nv1 + v * 10;
  float z[4];
#pragma unroll
  for (int j = 0; j < 4; j++) {
    int w = t + j * 256;
    float s = 0.f;
#pragma unroll
    for (int a = 0; a < 10; a++) s += nrow[a] * nv2[a * 1024 + w];
    z[j] = fmaxf(s, 0.f);
  }
  float m = fmaxf(fmaxf(z[0], z[1]), fmaxf(z[2], z[3]));
  for (int off = 32; off; off >>= 1) m = fmaxf(m, __shfl_down(m, off));
  if ((t & 63) == 0) red[t >> 6] = m;
  __syncthreads();
  m = fmaxf(fmaxf(red[0], red[1]), fmaxf(red[2], red[3]));
  float e[4], s = 0.f;
#pragma unroll
  for (int j = 0; j < 4; j++) { e[j] = __expf(z[j] - m); s += e[j]; }
  for (int off = 32; off; off >>= 1) s += __shfl_down(s, off);
  if ((t & 63) == 0) red[4 + (t >> 6)] = s;
  __syncthreads();
  s = red[4] + red[5] + red[6] + red[7];
  float inv = 1.0f / s;
#pragma unroll
  for (int j = 0; j < 4; j++) adp[(long)v * 1024 + t + j * 256] = f2b(e[j] * inv);
}

// ---------------- transpose 1024x1024 bf16 ----------------
__global__ __launch_bounds__(256) void k_transpose(const u16* __restrict__ in, u16* __restrict__ out) {
  __shared__ u16 tile[64 * 65];
  int w0 = blockIdx.x * 64, v0 = blockIdx.y * 64, t = threadIdx.x;
  int c = t & 63, r4 = t >> 6;
  for (int rr = r4; rr < 64; rr += 4) tile[rr * 65 + c] = in[(long)(v0 + rr) * 1024 + w0 + c];
  __syncthreads();
  for (int rr = r4; rr < 64; rr += 4) out[(long)(w0 + rr) * 1024 + v0 + c] = tile[c * 65 + rr];
}

// ---------------- start conv: h0[b][c][l][v] bf16 (chunk-local b) ----------------
__global__ __launch_bounds__(256) void k_start(const float* __restrict__ x, const float* __restrict__ sw,
                                               const float* __restrict__ sb, u16* __restrict__ h, int b0) {
  int bl = blockIdx.y, bg = b0 + bl, v0 = blockIdx.x * 64, t = threadIdx.x;
  __shared__ float xs[2 * 832];  // [i][v*13+l]
  for (int idx = t; idx < 2 * 832; idx += 256) {
    int i = idx / 832, rem = idx % 832;
    xs[idx] = x[((long)(bg * 2 + i) * 1024 + v0) * 13 + rem];
  }
  __syncthreads();
  int vl = t & 63, grp = t >> 6;
  for (int idx = grp; idx < 32 * 13; idx += 4) {
    int c = idx / 13, l = idx % 13;
    float val = sw[c * 2 + 0] * xs[vl * 13 + l] + sw[c * 2 + 1] * xs[832 + vl * 13 + l] + sb[c];
    h[((long)(bl * 32 + c) * 13 + l) * 1024 + v0 + vl] = f2b(val);
  }
}

// ---------------- gated dilated conv: hg = tanh(f)*sigmoid(g), bf16 out ----------------
// Chunk-local h/hg (b in [0,BCH)); hlast written with global batch index b0+b.
__global__ __launch_bounds__(256) void k_gate(const u16* __restrict__ h, u16* __restrict__ hg,
                                              u16* __restrict__ hlast,
                                              const float* __restrict__ fw, const float* __restrict__ fb,
                                              const float* __restrict__ gw, const float* __restrict__ gb,
                                              int Lin, int Lout, int d, int layer, int b0, int writehg) {
  int b = blockIdx.z, l = blockIdx.y, v = blockIdx.x * 256 + threadIdx.x;
  const u16* hp = h + ((long)b * 32 * Lin + l) * 1024 + v;
  float h0[32], h1[32];
#pragma unroll
  for (int ci = 0; ci < 32; ci++) {
    h0[ci] = b2f(hp[(long)ci * Lin * 1024]);
    h1[ci] = b2f(hp[(long)ci * Lin * 1024 + (long)d * 1024]);
  }
  const float* fwl = fw + layer * 2048;
  const float* gwl = gw + layer * 2048;
  u16 vals[32];
  for (int oc = 0; oc < 32; oc++) {
    float f = fb[layer * 32 + oc], g = gb[layer * 32 + oc];
    const float* fo = fwl + oc * 64;
    const float* go = gwl + oc * 64;
#pragma unroll
    for (int ci = 0; ci < 32; ci++) {
      f += fo[ci * 2] * h0[ci] + fo[ci * 2 + 1] * h1[ci];
      g += go[ci * 2] * h0[ci] + go[ci * 2 + 1] * h1[ci];
    }
    float ft = 2.f * __builtin_amdgcn_rcpf(1.f + __expf(-2.f * f)) - 1.f;
    float gt = __builtin_amdgcn_rcpf(1.f + __expf(-g));
    u16 val = f2b(ft * gt);
    vals[oc] = val;
    if (writehg) hg[((long)(b * 32 + oc) * Lout + l) * 1024 + v] = val;
  }
  if (l == Lout - 1) {
    u16* dst = hlast + ((long)((b0 + b) * 1024 + v)) * 256 + layer * 32;
#pragma unroll
    for (int jj = 0; jj < 32; jj++) dst[jj] = vals[jj];
  }
}

// ---------------- GEMM: C[m][n] = sum_k A[m][k]*Bt[n][k], bf16 in/out, fp32 acc ----------------
// 128x128 tile, BK=32, 256 thr = 4 waves (2x2 of 64x64), m97 structure.
__global__ __launch_bounds__(256) void k_gemm(const u16* __restrict__ A, const u16* __restrict__ Bt,
                                              u16* __restrict__ C, int M, int N, int K,
                                              const float* __restrict__ bias, int relu) {
  __shared__ __align__(16) u16 As[128 * 32];
  __shared__ __align__(16) u16 Bs[128 * 32];
  int t = threadIdx.x, wave = t >> 6, lane = t & 63;
  int m0 = blockIdx.y * 128, n0 = blockIdx.x * 128;
  int wr = (wave >> 1) * 64, wc = (wave & 1) * 64;
  int q = lane >> 4, r = lane & 15;
  f32x4 acc[4][4] = {};
  const u16* Ag = A + (long)(m0 + wave * 32 + (lane >> 2)) * K + (lane & 3) * 8;
  const u16* Bg = Bt + (long)(n0 + wave * 32 + (lane >> 2)) * K + (lane & 3) * 8;
  u16* Al = As + wave * 1024 + lane * 8;
  u16* Bl = Bs + wave * 1024 + lane * 8;
  for (int k0 = 0; k0 < K; k0 += 32) {
    __syncthreads();
    gld_lds16(Ag + k0, Al);
    gld_lds16(Ag + 16 * K + k0, Al + 512);
    gld_lds16(Bg + k0, Bl);
    gld_lds16(Bg + 16 * K + k0, Bl + 512);
    __syncthreads();
    bf16x8 af[4], bfr[4];
#pragma unroll
    for (int i = 0; i < 4; i++) {
      af[i] = *(const bf16x8*)(As + (wr + i * 16 + r) * 32 + q * 8);
      bfr[i] = *(const bf16x8*)(Bs + (wc + i * 16 + r) * 32 + q * 8);
    }
#pragma unroll
    for (int i = 0; i < 4; i++)
#pragma unroll
      for (int j = 0; j < 4; j++)
        acc[i][j] = __builtin_amdgcn_mfma_f32_16x16x32_bf16(af[i], bfr[j], acc[i][j], 0, 0, 0);
  }
#pragma unroll
  for (int i = 0; i < 4; i++) {
    int row = m0 + wr + i * 16 + q * 4;
#pragma unroll
    for (int j = 0; j < 4; j++) {
      int col = n0 + wc + j * 16 + r;
      float bv = bias ? bias[col] : 0.f;
#pragma unroll
      for (int rg = 0; rg < 4; rg++) {
        float vv = acc[i][j][rg] + bv;
        if (relu) vv = fmaxf(vv, 0.f);
        C[(long)(row + rg) * N + col] = f2b(vv);
      }
    }
  }
}

// ---------------- gc conv + residual + BN affine: h_new bf16 (chunk-local) ----------------
__global__ __launch_bounds__(256) void k_gc(const u16* __restrict__ hg, const u16* __restrict__ x1,
                                            const u16* __restrict__ x2, const u16* __restrict__ hold,
                                            u16* __restrict__ hnew,
                                            const float* __restrict__ gcw, const float* __restrict__ gcb,
                                            const float* __restrict__ bng, const float* __restrict__ bnb,
                                            int Lin, int Lout, int d, int layer) {
  int b = blockIdx.z, l = blockIdx.y, v = blockIdx.x * 256 + threadIdx.x;
  float in[96];
  long base = ((long)b * 32 * Lout + l) * 1024 + v;
#pragma unroll
  for (int ci = 0; ci < 32; ci++) {
    in[ci] = b2f(hg[base + (long)ci * Lout * 1024]);
    in[32 + ci] = b2f(x1[base + (long)ci * Lout * 1024]);
    in[64 + ci] = b2f(x2[base + (long)ci * Lout * 1024]);
  }
  const float rs = rsqrtf(1.f + 1e-5f);
  for (int oc = 0; oc < 32; oc++) {
    const float* w = gcw + (layer * 32 + oc) * 96;
    float a = gcb[layer * 32 + oc];
#pragma unroll
    for (int k = 0; k < 96; k++) a += w[k] * in[k];
    float res = b2f(hold[((long)(b * 32 + oc) * Lin + l + d) * 1024 + v]);
    float scale = bng[layer * 32 + oc] * rs;
    hnew[((long)(b * 32 + oc) * Lout + l) * 1024 + v] = f2b((a + res) * scale + bnb[layer * 32 + oc]);
  }
}

// ---------------- weight repacks (bf16) + summed skip bias ----------------
__global__ __launch_bounds__(256) void k_wprep(const float* __restrict__ skw, const float* __restrict__ skb,
                                               const float* __restrict__ e1w, u16* __restrict__ wcat,
                                               u16* __restrict__ e1bf, float* __restrict__ sbias) {
  int idx = blockIdx.x * 256 + threadIdx.x;
  if (idx < 65536) {
    int cp = idx >> 8, k = idx & 255, i = k >> 5, c = k & 31;
    wcat[idx] = f2b(skw[(i * 256 + cp) * 32 + c]);
  }
  int j = idx - 65536;
  if (j >= 0 && j < 131072) e1bf[j] = f2b(e1w[j]);
  if (idx < 256) {
    float s = 0.f;
    for (int i = 0; i < 8; i++) s += skb[i * 256 + idx];
    sbias[idx] = s;
  }
}

// ---------------- final 12-wide conv: out fp32 (batch chunk at r0) ----------------
__global__ __launch_bounds__(256) void k_e3(const u16* __restrict__ e1, const float* __restrict__ w2,
                                            const float* __restrict__ b2, float* __restrict__ out, int r0) {
  int idx = blockIdx.x * 256 + threadIdx.x;
  int b = r0 + (idx >> 10), v = idx & 1023;
  float acc[12];
#pragma unroll
  for (int o = 0; o < 12; o++) acc[o] = b2[o];
  const u16* row = e1 + (long)idx * 512;
  for (int ec = 0; ec < 512; ec += 8) {
    bf16x8 raw = *(const bf16x8*)(row + ec);
    float xv[8];
#pragma unroll
    for (int jj = 0; jj < 8; jj++) xv[jj] = b2f((u16)raw[jj]);
#pragma unroll
    for (int o = 0; o < 12; o++) {
      const float* w = w2 + o * 512 + ec;
#pragma unroll
      for (int jj = 0; jj < 8; jj++) acc[o] += w[jj] * xv[jj];
    }
  }
#pragma unroll
  for (int o = 0; o < 12; o++) out[((long)b * 12 + o) * 1024 + v] = acc[o];
}

extern "C" void kernel_launch(void* const* d_in, const int* in_sizes, int n_in,
                              void* d_out, int out_size, void* d_ws, size_t ws_size,
                              hipStream_t stream) {
  const float* x = (const float*)d_in[0];
  const float* start_w = (const float*)d_in[1];
  const float* start_b = (const float*)d_in[2];
  const float* nv1 = (const float*)d_in[3];
  const float* nv2 = (const float*)d_in[4];
  const float* filter_w = (const float*)d_in[5];
  const float* filter_b = (const float*)d_in[6];
  const float* gate_w = (const float*)d_in[7];
  const float* gate_b = (const float*)d_in[8];
  const float* skip_w = (const float*)d_in[9];
  const float* skip_b = (const float*)d_in[10];
  const float* gc_w = (const float*)d_in[11];
  const float* gc_b = (const float*)d_in[12];
  const float* bn_g = (const float*)d_in[13];
  const float* bn_b = (const float*)d_in[14];
  const float* end1_w = (const float*)d_in[15];
  const float* end1_b = (const float*)d_in[16];
  const float* end2_w = (const float*)d_in[17];
  const float* end2_b = (const float*)d_in[18];
  float* out = (float*)d_out;

  char* ws = (char*)d_ws;
  // ---- fixed region (38,142,976 B) ----
  u16* adp = (u16*)(ws + 0);                      //  2,097,152
  u16* adpT = (u16*)(ws + 2097152ull);            //  2,097,152
  u16* hlastBV = (u16*)(ws + 4194304ull);         // 33,554,432  (64*1024 rows x 256 cols bf16)
  u16* wcat = (u16*)(ws + 37748736ull);           //    131,072
  u16* e1bf = (u16*)(ws + 37879808ull);           //    262,144
  float* sbias = (float*)(ws + 38141952ull);      //      1,024
  const size_t o_pipe = 38142976ull;

  // ---- adaptive batch chunking: pick largest BCH whose footprint fits ws_size ----
  // needed(BCH) = o_pipe + BCH*3,997,696
  int BCH = 4;
  {
    const int cand[5] = {64, 32, 16, 8, 4};
    for (int ci = 0; ci < 5; ci++) {
      size_t need = o_pipe + (size_t)cand[ci] * 3997696ull;
      if (need <= ws_size) { BCH = cand[ci]; break; }
    }
  }
  // pipeline buffers (chunk-local, bf16)
  u16* hA = (u16*)(ws + o_pipe);                                   // BCH*32*13*1024 = BCH*851,968 B
  u16* hB = (u16*)(ws + o_pipe + (size_t)BCH * 851968ull);         // BCH*32*12*1024 = BCH*786,432 B
  u16* hg = (u16*)(ws + o_pipe + (size_t)BCH * 1638400ull);
  u16* x1 = (u16*)(ws + o_pipe + (size_t)BCH * 2424832ull);
  u16* x2 = (u16*)(ws + o_pipe + (size_t)BCH * 3211264ull);
  // end-phase aliases into (then-dead) pipeline region; BE*1,572,864 <= BCH*3,997,696 for BE=2*BCH
  int BE = (BCH * 2 > 64) ? 64 : BCH * 2;
  u16* srelu = (u16*)(ws + o_pipe);                                // BE*1024*256*2 = BE*524,288 B
  u16* e1c = (u16*)(ws + o_pipe + (size_t)BE * 524288ull);         // BE*1024*512*2 = BE*1,048,576 B

  static const int LinA[8] = {13, 12, 10, 9, 7, 6, 4, 3};
  static const int dilA[8] = {1, 2, 1, 2, 1, 2, 1, 2};

  k_wprep<<<769, 256, 0, stream>>>(skip_w, skip_b, end1_w, wcat, e1bf, sbias);
  k_adp<<<1024, 256, 0, stream>>>(nv1, nv2, adp);
  k_transpose<<<dim3(16, 16), 256, 0, stream>>>(adp, adpT);

  for (int b0 = 0; b0 < 64; b0 += BCH) {
    k_start<<<dim3(16, BCH), 256, 0, stream>>>(x, start_w, start_b, hA, b0);
    for (int i = 0; i < 8; i++) {
      int Li = LinA[i], d = dilA[i], Lo = Li - d;
      u16* hin = (i & 1) ? hB : hA;
      u16* hout = (i & 1) ? hA : hB;
      k_gate<<<dim3(4, Lo, BCH), 256, 0, stream>>>(hin, hg, hlastBV, filter_w, filter_b,
                                                   gate_w, gate_b, Li, Lo, d, i, b0, (i < 7) ? 1 : 0);
      if (i < 7) {
        int M = BCH * 32 * Lo;  // BCH>=4 => multiple of 128
        k_gemm<<<dim3(8, M / 128), 256, 0, stream>>>(hg, adpT, x1, M, 1024, 1024, nullptr, 0);
        k_gemm<<<dim3(8, M / 128), 256, 0, stream>>>(x1, adpT, x2, M, 1024, 1024, nullptr, 0);
        k_gc<<<dim3(4, Lo, BCH), 256, 0, stream>>>(hg, x1, x2, hin, hout, gc_w, gc_b,
                                                   bn_g, bn_b, Li, Lo, d, i);
      }
    }
  }

  for (int r0 = 0; r0 < 64; r0 += BE) {
    int Mc = BE * 1024;
    k_gemm<<<dim3(2, Mc / 128), 256, 0, stream>>>(hlastBV + (size_t)r0 * 1024 * 256, wcat, srelu,
                                                  Mc, 256, 256, sbias, 1);
    k_gemm<<<dim3(4, Mc / 128), 256, 0, stream>>>(srelu, e1bf, e1c, Mc, 512, 256, end1_b, 1);
    k_e3<<<BE * 4, 256, 0, stream>>>(e1c, end2_w, end2_b, out, r0);
  }
  (void)in_sizes; (void)n_in; (void)out_size;
}